// Round 8
// baseline (581.658 us; speedup 1.0000x reference)
//
#include <hip/hip_runtime.h>
#include <math.h>

#define H_DIM 7168
#define NEXP  256
#define NGRP  8
#define EPG   32
#define TOPKG 4
#define KSEL  8
#define NTOK  8192
#define SCALE_F 2.5f

#define TAU_E32 3.0e-6f
#define TAU_G32 6.0e-6f
#define TAU_EMF 3.0e-5f
#define TAU_GMF 5.0e-5f

#define BT3   128                 // tokens per mfma block (r6-verified geometry)
#define NKT   (H_DIM / 32)        // 224 k-tiles total

// fp32 fallback GEMM config (KS=4)
#define KS4   4
#define KSPAN4 (H_DIM / KS4)      // 1792
#define BT2   64
#define BK2   16
#define NT2   (KSPAN4 / BK2)      // 112

// fused fallback config
#define BT    32
#define BK    16
#define NTILE (H_DIM / BK)
#define NTHR  256

#define BTG   16

#define PART4_BYTES ((size_t)4 * NTOK * NEXP * sizeof(float))   // 32 MB
#define PART8_BYTES ((size_t)8 * NTOK * NEXP * sizeof(float))   // 64 MB
#define FLAG_BYTES ((size_t)(((1 + NTOK) * 4 + 127) / 128) * 128)
#define WPACK_BYTES ((size_t)NKT * 32768)

typedef float f4v __attribute__((ext_vector_type(4)));
typedef short bf16x8 __attribute__((ext_vector_type(8)));
typedef float f32x16 __attribute__((ext_vector_type(16)));

__device__ __forceinline__ void gload16(const void* g, void* l) {
  __builtin_amdgcn_global_load_lds((const __attribute__((address_space(1))) unsigned int*)g,
                                   (__attribute__((address_space(3))) unsigned int*)l,
                                   16, 0, 0);
}

__device__ __forceinline__ void bf16split(float x, unsigned short& h, unsigned short& l) {
  unsigned int u  = __float_as_uint(x);
  unsigned int r  = u + 0x7FFFu + ((u >> 16) & 1u);      // RNE to bf16
  h = (unsigned short)(r >> 16);
  float hf = __uint_as_float(r & 0xFFFF0000u);
  float lo = x - hf;                                      // exact
  unsigned int ul = __float_as_uint(lo);
  unsigned int rl = ul + 0x7FFFu + ((ul >> 16) & 1u);
  l = (unsigned short)(rl >> 16);
}

__device__ __forceinline__ void split8(const f4v f0, const f4v f1, bf16x8& h8, bf16x8& l8) {
  #pragma unroll
  for (int j = 0; j < 8; ++j) {
    const float x = (j < 4) ? f0[j] : f1[j - 4];
    unsigned short hh, ll;
    bf16split(x, hh, ll);
    h8[j] = (short)hh;
    l8[j] = (short)ll;
  }
}

// ============================================================================
// W pre-pack: fragment-ordered bf16 hi/lo slabs (layout VERIFIED rounds 4-7).
// ============================================================================
__global__ __launch_bounds__(256)
void moe_wpack(const float* __restrict__ wg, unsigned short* __restrict__ wpack,
               int* __restrict__ flaglist) {
  if (blockIdx.x == 0 && blockIdx.y == 0 && threadIdx.x == 0) flaglist[0] = 0;
  const int kt   = blockIdx.x;
  const int half = blockIdx.y;
  const int tid  = threadIdx.x;
  #pragma unroll
  for (int i = 0; i < 4; ++i) {
    const int u    = tid + 256 * (4 * half + i);
    const int slab = u >> 6;
    const int lane = u & 63;
    const int d    = slab & 1;
    const int subK = (slab >> 1) & 1;
    const int expCg = slab >> 2;
    const int e = expCg * 32 + (lane & 31);
    const int k = kt * 32 + subK * 16 + (lane >> 5) * 8;
    const float* src = wg + (size_t)e * H_DIM + k;
    const f4v f0 = *(const f4v*)(src);
    const f4v f1 = *(const f4v*)(src + 4);
    bf16x8 o;
    #pragma unroll
    for (int j = 0; j < 8; ++j) {
      const float x = (j < 4) ? f0[j] : f1[j - 4];
      unsigned short hh, ll;
      bf16split(x, hh, ll);
      o[j] = (short)(d ? ll : hh);
    }
    *(bf16x8*)(wpack + (size_t)kt * 16384 + slab * 512 + lane * 8) = o;
  }
}

// ============================================================================
// MFMA split GEMM — EXACT round-6 body (148 us verified at KSX=4), templated
// on K-split.  KSX=8: grid 512 = 2 blk/CU, ks = bid&7 = XCD id (wpack slice
// 896 KB fully L2-resident per XCD).  KSX=4: exact r6 launch (grid 256).
// ============================================================================
template <int KSX>
__global__ __launch_bounds__(512, 4)
void moe_gemm_mfma(const float* __restrict__ xg,
                   const unsigned short* __restrict__ wpack,
                   float* __restrict__ part) {
  constexpr int KSPANX = H_DIM / KSX;
  constexpr int NT3X   = KSPANX / 32;
  __shared__ __align__(16) unsigned short a_sl[2][16][512];   // 32 KB

  const int tid  = threadIdx.x;
  const int lane = tid & 63;
  const int wv   = tid >> 6;
  const int tokG = wv >> 2;         // 0..1 -> rows tokG*64..
  const int expG = wv & 3;

  const int bid  = blockIdx.x;
  int ks, tokb;
  if constexpr (KSX == 8) { ks = bid & 7;        tokb = bid >> 3; }
  else                    { ks = (bid & 7) >> 1; tokb = ((bid >> 3) << 1) | (bid & 1); }
  const int t0   = tokb * BT3;
  const int kbase = ks * KSPANX;

  const bool stg = (tid & 1) == 0;
  const int arow = tid >> 2;          // 0..127
  const int asub = (tid >> 1) & 1;
  const int arg  = arow >> 5;         // 0..3
  const int ar   = arow & 31;
  const int sh   = (arg * 2 + asub) * 2;
  const float* axp = xg + (size_t)(t0 + arow) * H_DIM + kbase + asub * 16;

  f32x16 acc[2][2];
  #pragma unroll
  for (int tc = 0; tc < 2; ++tc)
    #pragma unroll
    for (int ec = 0; ec < 2; ++ec)
      #pragma unroll
      for (int r = 0; r < 16; ++r) acc[tc][ec][r] = 0.0f;

  f4v xr0, xr1;

  auto loadX = [&](int t) {
    if (!stg) return;
    const float* p = axp + t * 32;
    xr0 = *(const f4v*)(p);
    xr1 = *(const f4v*)(p + 4);
  };
  auto writeA = [&](int buf) {
    if (!stg) return;
    bf16x8 h0, l0;
    split8(xr0, xr1, h0, l0);
    *(bf16x8*)&a_sl[buf][sh][ar * 8 + ((asub * 0))]     = h0;
    *(bf16x8*)&a_sl[buf][sh + 1][ar * 8]                = l0;
  };
  // NOTE: r6 stager loaded 16 floats (two 8-k halves). Keep exact r6 mapping:
  f4v yr0, yr1;
  auto loadX2 = [&](int t) {
    if (!stg) return;
    const float* p = axp + t * 32;
    xr0 = *(const f4v*)(p);
    xr1 = *(const f4v*)(p + 4);
    yr0 = *(const f4v*)(p + 8);
    yr1 = *(const f4v*)(p + 12);
  };
  auto writeA2 = [&](int buf) {
    if (!stg) return;
    bf16x8 h0, l0, h1, l1;
    split8(xr0, xr1, h0, l0);
    split8(yr0, yr1, h1, l1);
    *(bf16x8*)&a_sl[buf][sh][ar * 8]            = h0;   // k 0..7  -> pos ar
    *(bf16x8*)&a_sl[buf][sh][(32 + ar) * 8]     = h1;   // k 8..15 -> pos ar+32
    *(bf16x8*)&a_sl[buf][sh + 1][ar * 8]        = l0;
    *(bf16x8*)&a_sl[buf][sh + 1][(32 + ar) * 8] = l1;
  };
  auto loadB = [&](int t, bf16x8 (&B)[2][2][2]) {
    const unsigned short* bp = wpack + (size_t)(ks * NT3X + t) * 16384 + lane * 8;
    #pragma unroll
    for (int s = 0; s < 2; ++s)
      #pragma unroll
      for (int ec = 0; ec < 2; ++ec)
        #pragma unroll
        for (int d = 0; d < 2; ++d)
          B[s][ec][d] = *(const bf16x8*)(bp + (size_t)((((expG * 2 + ec) * 2 + s) * 2 + d) * 512));
  };
  auto compute = [&](int buf, bf16x8 (&B)[2][2][2]) {
    #pragma unroll
    for (int s = 0; s < 2; ++s) {
      bf16x8 ah2[2], al2[2];
      #pragma unroll
      for (int tc = 0; tc < 2; ++tc) {
        const int sa = ((tokG * 2 + tc) * 2 + s) * 2;
        ah2[tc] = *(const bf16x8*)&a_sl[buf][sa][lane * 8];
        al2[tc] = *(const bf16x8*)&a_sl[buf][sa + 1][lane * 8];
      }
      #pragma unroll
      for (int tc = 0; tc < 2; ++tc)
        #pragma unroll
        for (int ec = 0; ec < 2; ++ec) {
          acc[tc][ec] = __builtin_amdgcn_mfma_f32_32x32x16_bf16(ah2[tc], B[s][ec][0], acc[tc][ec], 0, 0, 0);
          acc[tc][ec] = __builtin_amdgcn_mfma_f32_32x32x16_bf16(ah2[tc], B[s][ec][1], acc[tc][ec], 0, 0, 0);
          acc[tc][ec] = __builtin_amdgcn_mfma_f32_32x32x16_bf16(al2[tc], B[s][ec][0], acc[tc][ec], 0, 0, 0);
        }
    }
  };

  bf16x8 BA[2][2][2], BB[2][2][2];

  loadX2(0);
  loadB(0, BA);
  writeA2(0);
  asm volatile("s_waitcnt lgkmcnt(0)\n\ts_barrier" ::: "memory");

  #pragma unroll 1
  for (int k = 0; k < NT3X / 2; ++k) {
    const int t = 2 * k;
    loadX2(t + 1);
    loadB(t + 1, BB);
    compute(0, BA);
    writeA2(1);
    asm volatile("s_waitcnt lgkmcnt(0)\n\ts_barrier" ::: "memory");
    const bool more = (t + 2 < NT3X);
    if (more) { loadX2(t + 2); loadB(t + 2, BA); }
    compute(1, BB);
    if (more) writeA2(0);
    asm volatile("s_waitcnt lgkmcnt(0)\n\ts_barrier" ::: "memory");
  }

  #pragma unroll
  for (int tc = 0; tc < 2; ++tc)
    #pragma unroll
    for (int ec = 0; ec < 2; ++ec)
      #pragma unroll
      for (int reg = 0; reg < 16; ++reg) {
        const int row = (reg & 3) + 8 * (reg >> 2) + 4 * (lane >> 5);
        const int tok = t0 + tokG * 64 + tc * 32 + row;
        const int e   = expG * 64 + ec * 32 + (lane & 31);
        part[((size_t)ks * NTOK + tok) * NEXP + e] = acc[tc][ec][reg];
      }
}

// ============================================================================
// fp32 fallback GEMM (round-3 verified).
// ============================================================================
__global__ __launch_bounds__(256, 2)
void moe_gemm_part(const float* __restrict__ xg,
                   const float* __restrict__ wg,
                   float* __restrict__ part,
                   int* __restrict__ flaglist) {
  __shared__ __align__(16) float w_t[2][4][NEXP][4];
  __shared__ __align__(16) float x_t[2][4][BT2][4];

  if (blockIdx.x == 0 && blockIdx.y == 0 && threadIdx.x == 0) flaglist[0] = 0;

  const int tid  = threadIdx.x;
  const int lane = tid & 63;
  const int wave = tid >> 6;
  const int c32  = lane & 31;
  const int tb   = (wave << 1) | (lane >> 5);
  const int t0   = blockIdx.x * BT2;
  const int ks   = blockIdx.y;
  const int kbase = ks * KSPAN4;

  float acc[8][8];
  #pragma unroll
  for (int i = 0; i < 8; ++i)
    #pragma unroll
    for (int j = 0; j < 8; ++j) acc[i][j] = 0.0f;

  auto stage = [&](int b, int t) {
    const int k0 = kbase + t * BK2;
    #pragma unroll
    for (int h = 0; h < 4; ++h)
      gload16(wg + (size_t)(h * 64 + lane) * H_DIM + k0 + 4 * wave,
              &w_t[b][wave][h * 64][0]);
    gload16(xg + (size_t)(t0 + lane) * H_DIM + k0 + 4 * wave, &x_t[b][wave][0][0]);
  };

  auto compute = [&](int b) {
    float accp[8][8];
    #pragma unroll
    for (int i = 0; i < 8; ++i)
      #pragma unroll
      for (int j = 0; j < 8; ++j) accp[i][j] = 0.0f;
    #pragma unroll
    for (int kq = 0; kq < 4; ++kq) {
      f4v wf[8], xf[8];
      #pragma unroll
      for (int j = 0; j < 8; ++j) wf[j] = *(const f4v*)&w_t[b][kq][c32 + 32 * j][0];
      #pragma unroll
      for (int i = 0; i < 8; ++i) xf[i] = *(const f4v*)&x_t[b][kq][tb * 8 + i][0];
      #pragma unroll
      for (int i = 0; i < 8; ++i)
        #pragma unroll
        for (int j = 0; j < 8; ++j) {
          accp[i][j] = fmaf(xf[i][0], wf[j][0], accp[i][j]);
          accp[i][j] = fmaf(xf[i][1], wf[j][1], accp[i][j]);
          accp[i][j] = fmaf(xf[i][2], wf[j][2], accp[i][j]);
          accp[i][j] = fmaf(xf[i][3], wf[j][3], accp[i][j]);
        }
    }
    #pragma unroll
    for (int i = 0; i < 8; ++i)
      #pragma unroll
      for (int j = 0; j < 8; ++j) acc[i][j] += accp[i][j];
  };

  stage(0, 0);
  __syncthreads();
  for (int t = 0; t < NT2; ++t) {
    const int cur = t & 1;
    if (t + 1 < NT2) stage(cur ^ 1, t + 1);
    compute(cur);
    __syncthreads();
  }

  float* pp = part + ((size_t)ks * NTOK + t0) * NEXP;
  #pragma unroll
  for (int i = 0; i < 8; ++i)
    #pragma unroll
    for (int j = 0; j < 8; ++j)
      pp[(size_t)(tb * 8 + i) * NEXP + c32 + 32 * j] = acc[i][j];
}

// ============================================================================
// Phase 2: sum KSX partials -> gating; flagged tokens -> flaglist.
// BTG=16 tokens/block, grid 512 = 2 blocks/CU.
// ============================================================================
template <int KSX>
__global__ __launch_bounds__(256, 2)
void moe_gate_from_part(const float* __restrict__ bg,
                        const float* __restrict__ part,
                        int* __restrict__ flaglist,
                        float* __restrict__ out,
                        float tauE, float tauG) {
  __shared__ __align__(16) float logits[BTG * NEXP];

  const int tid  = threadIdx.x;
  const int lane = tid & 63;
  const int wave = tid >> 6;
  const int t0   = blockIdx.x * BTG;

  #pragma unroll
  for (int m = 0; m < (BTG * 64) / 256; ++m) {
    const int idx = tid + 256 * m;
    const int tt  = idx >> 6;
    const int ch  = idx & 63;
    f4v s;
    s[0] = 0.f; s[1] = 0.f; s[2] = 0.f; s[3] = 0.f;
    #pragma unroll
    for (int sp = 0; sp < KSX; ++sp) {
      const f4v v = *(const f4v*)&part[(((size_t)sp * NTOK) + t0 + tt) * NEXP + 4 * ch];
      s[0] += v[0]; s[1] += v[1]; s[2] += v[2]; s[3] += v[3];
    }
    *(f4v*)&logits[tt * NEXP + 4 * ch] = s;
  }
  __syncthreads();

  const f4v bias4 = *(const f4v*)(bg + 4 * lane);

  for (int tk = wave; tk < BTG; tk += 4) {
    const float* lrow = logits + tk * NEXP;
    const f4v lz = *(const f4v*)&lrow[4 * lane];
    float sc[4], vc[4];
    #pragma unroll
    for (int j = 0; j < 4; ++j) {
      sc[j] = 1.0f / (1.0f + expf(-lz[j]));
      vc[j] = sc[j] + bias4[j];
    }
    float a1 = -INFINITY, a2 = -INFINITY;
    #pragma unroll
    for (int j = 0; j < 4; ++j) {
      const float v = vc[j];
      if (v > a1) { a2 = a1; a1 = v; } else if (v > a2) { a2 = v; }
    }
    #pragma unroll
    for (int dstep = 0; dstep < 3; ++dstep) {
      const int d = 1 << dstep;
      const float o1 = __shfl_xor(a1, d);
      const float o2 = __shfl_xor(a2, d);
      if (o1 > a1) { a2 = fmaxf(a1, o2); a1 = o1; }
      else         { a2 = fmaxf(a2, o1); }
    }
    const float gs = a1 + a2;
    float gsv[8];
    #pragma unroll
    for (int h = 0; h < 8; ++h) gsv[h] = __shfl(gs, h * 8);
    int selmask = 0; float r4v = 0.0f, r5v = 0.0f;
    #pragma unroll
    for (int g = 0; g < 8; ++g) {
      int rank = 0;
      #pragma unroll
      for (int h = 0; h < 8; ++h)
        rank += (gsv[h] > gsv[g]) || ((gsv[h] == gsv[g]) && (h < g));
      if (rank < TOPKG) selmask |= 1 << g;
      if (rank == TOPKG - 1) r4v = gsv[g];
      if (rank == TOPKG)     r5v = gsv[g];
    }
    const bool msel = (selmask >> (lane >> 3)) & 1;
    float mv[4];
    #pragma unroll
    for (int j = 0; j < 4; ++j) mv[j] = msel ? vc[j] : -INFINITY;

    int rem = 0xF;
    float wsum = 0.0f, mys = 0.0f, prev = 0.0f, minm = 1e30f;
    int myidx = 0;
    #pragma unroll
    for (int it = 0; it < KSEL + 1; ++it) {
      float bv = -INFINITY, bs = 0.0f; int bi = 0x7FFFFFFF;
      #pragma unroll
      for (int j = 0; j < 4; ++j)
        if ((rem >> j) & 1) {
          if (mv[j] > bv) { bv = mv[j]; bs = sc[j]; bi = 4 * lane + j; }
        }
      #pragma unroll
      for (int dstep = 5; dstep >= 0; --dstep) {
        const int d = 1 << dstep;
        const float ov = __shfl_xor(bv, d);
        const float os = __shfl_xor(bs, d);
        const int   oi = __shfl_xor(bi, d);
        if ((ov > bv) || ((ov == bv) && (oi < bi))) { bv = ov; bs = os; bi = oi; }
      }
      if (it > 0) minm = fminf(minm, prev - bv);
      prev = bv;
      if (it < KSEL) {
        wsum += bs;
        if (lane == it) { myidx = bi; mys = bs; }
        if ((bi >> 2) == lane) rem &= ~(1 << (bi & 3));
      }
    }
    const bool flagged = (minm < tauE) || ((r4v - r5v) < tauG);
    if (flagged) {
      if (lane == 0) {
        const int p = atomicAdd(&flaglist[0], 1);
        flaglist[1 + p] = t0 + tk;
      }
    } else if (lane < KSEL) {
      out[(size_t)(t0 + tk) * KSEL + lane] = (float)myidx;
      out[(size_t)NTOK * KSEL + (size_t)(t0 + tk) * KSEL + lane] =
          mys / (wsum + 1e-20f) * SCALE_F;
    }
  }
}

// ============================================================================
// Phase 3: f64 refine, one block per flagged token, 2-way ILP dots.
// ============================================================================
template <int KSX>
__global__ __launch_bounds__(256, 2)
void moe_refine(const float* __restrict__ xg,
                const float* __restrict__ wg,
                const float* __restrict__ bg,
                const float* __restrict__ part,
                const int* __restrict__ flaglist,
                float* __restrict__ out) {
  __shared__ __align__(16) float xrow[H_DIM];
  __shared__ float  sfc32[NEXP];
  __shared__ int    cand_id[80];
  __shared__ double cand_sfc[80];
  __shared__ double cand_sv[80];

  const int tid  = threadIdx.x;
  const int lane = tid & 63;
  const int wave = tid >> 6;
  const int count = flaglist[0];

  for (int item = blockIdx.x; item < count; item += gridDim.x) {
    const int tok = flaglist[1 + item];

    {
      float lg = 0.0f;
      #pragma unroll
      for (int sp = 0; sp < KSX; ++sp)
        lg += part[((size_t)sp * NTOK + tok) * NEXP + tid];
      sfc32[tid] = 1.0f / (1.0f + expf(-lg)) + bg[tid];
    }
    for (int i = tid; i < H_DIM / 4; i += 256)
      *(f4v*)&xrow[4 * i] = *(const f4v*)&xg[(size_t)tok * H_DIM + 4 * i];
    __syncthreads();

    {
      const int g  = 2 * wave + (lane >> 5);
      const int el = lane & 31;
      const int e  = g * EPG + el;
      float vv = sfc32[e];
      #pragma unroll 1
      for (int it = 0; it < 10; ++it) {
        float bv = vv; int bi = e;
        #pragma unroll
        for (int dstep = 4; dstep >= 0; --dstep) {
          const int d = 1 << dstep;
          const float ov = __shfl_xor(bv, d);
          const int   oi = __shfl_xor(bi, d);
          if ((ov > bv) || ((ov == bv) && (oi < bi))) { bv = ov; bi = oi; }
        }
        if (el == 0) cand_id[g * 10 + it] = bi;
        if (e == bi) vv = -INFINITY;
      }
    }
    __syncthreads();

    #pragma unroll 1
    for (int cc = wave; cc < 40; cc += 4) {
      const int c1 = cc, c2 = cc + 40;
      const int e1 = cand_id[c1], e2 = cand_id[c2];
      const float* w1 = wg + (size_t)e1 * H_DIM;
      const float* w2 = wg + (size_t)e2 * H_DIM;
      double a1[4], a2d[4];
      #pragma unroll
      for (int r = 0; r < 4; ++r) { a1[r] = 0.0; a2d[r] = 0.0; }
      #pragma unroll 1
      for (int base = 0; base < H_DIM; base += 256) {
        #pragma unroll
        for (int r = 0; r < 4; ++r) {
          const int kk = base + 64 * r + lane;
          const double xv = (double)xrow[kk];
          a1[r]  = fma(xv, (double)w1[kk], a1[r]);
          a2d[r] = fma(xv, (double)w2[kk], a2d[r]);
        }
      }
      double s1 = (a1[0] + a1[1]) + (a1[2] + a1[3]);
      double s2 = (a2d[0] + a2d[1]) + (a2d[2] + a2d[3]);
      #pragma unroll
      for (int dstep = 5; dstep >= 0; --dstep) {
        s1 += __shfl_xor(s1, 1 << dstep);
        s2 += __shfl_xor(s2, 1 << dstep);
      }
      if (lane == 0) {
        const double sd1 = 1.0 / (1.0 + exp(-s1));
        const double sd2 = 1.0 / (1.0 + exp(-s2));
        cand_sfc[c1] = sd1 + (double)bg[e1];  cand_sv[c1] = sd1;
        cand_sfc[c2] = sd2 + (double)bg[e2];  cand_sv[c2] = sd2;
      }
    }
    __syncthreads();

    if (wave == 0) {
      double gsd = -1e300;
      if (lane < NGRP) {
        double A = -1e300, B2 = -1e300;
        #pragma unroll
        for (int i = 0; i < 10; ++i) {
          const double v = cand_sfc[lane * 10 + i];
          if (v > A) { B2 = A; A = v; } else if (v > B2) { B2 = v; }
        }
        gsd = A + B2;
      }
      double gsvd[8];
      #pragma unroll
      for (int h = 0; h < 8; ++h) gsvd[h] = __shfl(gsd, h);
      int selm = 0;
      #pragma unroll
      for (int g = 0; g < 8; ++g) {
        int rank = 0;
        #pragma unroll
        for (int h = 0; h < 8; ++h)
          rank += (gsvd[h] > gsvd[g]) || ((gsvd[h] == gsvd[g]) && (h < g));
        if (rank < TOPKG) selm |= 1 << g;
      }
      const int cA = lane, cB = lane + 64;
      double vA = ((selm >> (cA / 10)) & 1) ? cand_sfc[cA] : -1e300;
      int eA = cand_id[cA];
      double vB = -1e300; int eB = 0x7FFFFFFF;
      if (cB < 80) {
        if ((selm >> (cB / 10)) & 1) vB = cand_sfc[cB];
        eB = cand_id[cB];
      }
      float wsum = 0.0f, mys = 0.0f; int myidx = 0;
      #pragma unroll
      for (int it = 0; it < KSEL; ++it) {
        double bv; int be, bc;
        if ((vB > vA) || ((vB == vA) && (eB < eA))) { bv = vB; be = eB; bc = cB; }
        else { bv = vA; be = eA; bc = cA; }
        #pragma unroll
        for (int dstep = 5; dstep >= 0; --dstep) {
          const int d = 1 << dstep;
          const double ov = __shfl_xor(bv, d);
          const int   oe = __shfl_xor(be, d);
          const int   oc = __shfl_xor(bc, d);
          if ((ov > bv) || ((ov == bv) && (oe < be))) { bv = ov; be = oe; bc = oc; }
        }
        const float sw = (float)cand_sv[bc];
        wsum += sw;
        if (lane == it) { myidx = be; mys = sw; }
        if (cA == bc) vA = -1e300;
        if (cB == bc) vB = -1e300;
      }
      if (lane < KSEL) {
        out[(size_t)tok * KSEL + lane] = (float)myidx;
        out[(size_t)NTOK * KSEL + (size_t)tok * KSEL + lane] =
            mys / (wsum + 1e-20f) * SCALE_F;
      }
    }
    __syncthreads();
  }
}

// ============================================================================
// Full fused fallback (round-1 verified) — used only if ws is tiny.
// ============================================================================
__global__ __launch_bounds__(NTHR, 1)
void moe_gate_fused(const float* __restrict__ xg,
                    const float* __restrict__ wg,
                    const float* __restrict__ bg,
                    float* __restrict__ out) {
  __shared__ __align__(16) float lds_w[2][BK * NEXP];
  __shared__ __align__(16) float lds_x[2][BK * BT];
  __shared__ int    lds_flag[BT];
  __shared__ int    cand_id[80];
  __shared__ double cand_sfc[80];
  __shared__ double cand_sv[80];

  const int tid  = threadIdx.x;
  const int lane = tid & 63;
  const int wave = tid >> 6;
  const int er   = tid & 63;
  const int tr   = tid >> 6;
  const int t0   = blockIdx.x * BT;
  const int wkq = tid & 3;
  const int wet = tid >> 2;
  const int xkq = tid & 3;
  const int xtq = tid >> 2;

  float acc[8][4];
  #pragma unroll
  for (int i = 0; i < 8; ++i)
    #pragma unroll
    for (int j = 0; j < 4; ++j) acc[i][j] = 0.0f;

  const f4v bias4 = *(const f4v*)(bg + 4 * lane);
  f4v wv[4];
  f4v xv;

  auto load_tile = [&](int t) {
    const int k0 = t * BK;
    const float* wp = wg + (size_t)wet * H_DIM + k0 + 4 * wkq;
    wv[0] = *(const f4v*)(wp);
    wv[1] = *(const f4v*)(wp + (size_t)64  * H_DIM);
    wv[2] = *(const f4v*)(wp + (size_t)128 * H_DIM);
    wv[3] = *(const f4v*)(wp + (size_t)192 * H_DIM);
    if (tid < 128)
      xv = *(const f4v*)(xg + (size_t)(t0 + xtq) * H_DIM + k0 + 4 * xkq);
  };

  auto stage_tile = [&](int b) {
    #pragma unroll
    for (int p = 0; p < 4; ++p) {
      const int e = 64 * p + wet;
      const int g = e >> 2, r = e & 3;
      #pragma unroll
      for (int j = 0; j < 4; ++j) {
        const int k = 4 * wkq + j;
        lds_w[b][k * NEXP + 4 * (g ^ wkq) + r] = wv[p][j];
      }
    }
    if (tid < 128) {
      #pragma unroll
      for (int j = 0; j < 4; ++j) {
        const int k = 4 * xkq + j;
        lds_x[b][k * BT + (xtq ^ (xkq << 3))] = xv[j];
      }
    }
  };

  auto compute_tile = [&](int b) {
    float accp[8][4];
    #pragma unroll
    for (int i = 0; i < 8; ++i)
      #pragma unroll
      for (int j = 0; j < 4; ++j) accp[i][j] = 0.0f;
    #pragma unroll
    for (int k = 0; k < BK; ++k) {
      const int kq = k >> 2;
      const f4v wf  = *(const f4v*)&lds_w[b][k * NEXP + 4 * (er ^ kq)];
      const int xb  = k * BT + 8 * (tr ^ kq);
      const f4v xf0 = *(const f4v*)&lds_x[b][xb];
      const f4v xf1 = *(const f4v*)&lds_x[b][xb + 4];
      #pragma unroll
      for (int i = 0; i < 4; ++i)
        #pragma unroll
        for (int j = 0; j < 4; ++j) {
          accp[i][j]     = fmaf(xf0[i], wf[j], accp[i][j]);
          accp[i + 4][j] = fmaf(xf1[i], wf[j], accp[i + 4][j]);
        }
    }
    #pragma unroll
    for (int i = 0; i < 8; ++i)
      #pragma unroll
      for (int j = 0; j < 4; ++j) acc[i][j] += accp[i][j];
  };

  load_tile(0);
  stage_tile(0);
  __syncthreads();
  for (int t = 0; t < NTILE; ++t) {
    const int cur = t & 1;
    if (t + 1 < NTILE) load_tile(t + 1);
    compute_tile(cur);
    if (t + 1 < NTILE) stage_tile(cur ^ 1);
    __syncthreads();
  }

  float* logits = &lds_w[0][0];
  #pragma unroll
  for (int i = 0; i < 8; ++i) {
    f4v o;
    o[0] = acc[i][0]; o[1] = acc[i][1]; o[2] = acc[i][2]; o[3] = acc[i][3];
    *(f4v*)&logits[(8 * tr + i) * NEXP + 4 * er] = o;
  }
  if (tid < BT) lds_flag[tid] = 0;
  __syncthreads();

  for (int tk = wave; tk < BT; tk += 4) {
    const float* lrow = logits + tk * NEXP;
    const f4v lz = *(const f4v*)&lrow[4 * lane];
    float sc[4], vc[4];
    #pragma unroll
    for (int j = 0; j < 4; ++j) {
      sc[j] = 1.0f / (1.0f + expf(-lz[j]));
      vc[j] = sc[j] + bias4[j];
    }
    float a1 = -INFINITY, a2 = -INFINITY;
    #pragma unroll
    for (int j = 0; j < 4; ++j) {
      const float v = vc[j];
      if (v > a1) { a2 = a1; a1 = v; } else if (v > a2) { a2 = v; }
    }
    #pragma unroll
    for (int dstep = 0; dstep < 3; ++dstep) {
      const int d = 1 << dstep;
      const float o1 = __shfl_xor(a1, d);
      const float o2 = __shfl_xor(a2, d);
      if (o1 > a1) { a2 = fmaxf(a1, o2); a1 = o1; }
      else         { a2 = fmaxf(a2, o1); }
    }
    const float gs = a1 + a2;
    float gsv[8];
    #pragma unroll
    for (int h = 0; h < 8; ++h) gsv[h] = __shfl(gs, h * 8);
    int selmask = 0; float r4v = 0.0f, r5v = 0.0f;
    #pragma unroll
    for (int g = 0; g < 8; ++g) {
      int rank = 0;
      #pragma unroll
      for (int h = 0; h < 8; ++h)
        rank += (gsv[h] > gsv[g]) || ((gsv[h] == gsv[g]) && (h < g));
      if (rank < TOPKG) selmask |= 1 << g;
      if (rank == TOPKG - 1) r4v = gsv[g];
      if (rank == TOPKG)     r5v = gsv[g];
    }
    const bool msel = (selmask >> (lane >> 3)) & 1;
    float mv[4];
    #pragma unroll
    for (int j = 0; j < 4; ++j) mv[j] = msel ? vc[j] : -INFINITY;

    int rem = 0xF;
    float wsum = 0.0f, mys = 0.0f, prev = 0.0f, minm = 1e30f;
    int myidx = 0;
    #pragma unroll
    for (int it = 0; it < KSEL + 1; ++it) {
      float bv = -INFINITY, bs = 0.0f; int bi = 0x7FFFFFFF;
      #pragma unroll
      for (int j = 0; j < 4; ++j)
        if ((rem >> j) & 1) {
          if (mv[j] > bv) { bv = mv[j]; bs = sc[j]; bi = 4 * lane + j; }
        }
      #pragma unroll
      for (int dstep = 5; dstep >= 0; --dstep) {
        const int d = 1 << dstep;
        const float ov = __shfl_xor(bv, d);
        const float os = __shfl_xor(bs, d);
        const int   oi = __shfl_xor(bi, d);
        if ((ov > bv) || ((ov == bv) && (oi < bi))) { bv = ov; bs = os; bi = oi; }
      }
      if (it > 0) minm = fminf(minm, prev - bv);
      prev = bv;
      if (it < KSEL) {
        wsum += bs;
        if (lane == it) { myidx = bi; mys = bs; }
        if ((bi >> 2) == lane) rem &= ~(1 << (bi & 3));
      }
    }
    const bool flagged = (minm < TAU_E32) || ((r4v - r5v) < TAU_G32);
    if (flagged) {
      if (lane == 0) lds_flag[tk] = 1;
    } else if (lane < KSEL) {
      out[(size_t)(t0 + tk) * KSEL + lane] = (float)myidx;
      out[(size_t)NTOK * KSEL + (size_t)(t0 + tk) * KSEL + lane] =
          mys / (wsum + 1e-20f) * SCALE_F;
    }
  }
  __syncthreads();

  #pragma unroll 1
  for (int tk = 0; tk < BT; ++tk) {
    if (!lds_flag[tk]) continue;
    {
      const int g  = 2 * wave + (lane >> 5);
      const int el = lane & 31;
      const int e  = g * EPG + el;
      const float z = logits[tk * NEXP + e];
      float vv = 1.0f / (1.0f + expf(-z)) + bg[e];
      #pragma unroll 1
      for (int it = 0; it < 10; ++it) {
        float bv = vv; int bi = e;
        #pragma unroll
        for (int dstep = 4; dstep >= 0; --dstep) {
          const int d = 1 << dstep;
          const float ov = __shfl_xor(bv, d);
          const int   oi = __shfl_xor(bi, d);
          if ((ov > bv) || ((ov == bv) && (oi < bi))) { bv = ov; bi = oi; }
        }
        if (el == 0) cand_id[g * 10 + it] = bi;
        if (e == bi) vv = -INFINITY;
      }
    }
    __syncthreads();
    #pragma unroll 1
    for (int c = wave; c < 80; c += 4) {
      const int e = cand_id[c];
      const float* xr = xg + (size_t)(t0 + tk) * H_DIM;
      const float* wr = wg + (size_t)e * H_DIM;
      double ad = 0.0;
      for (int kk = lane; kk < H_DIM; kk += 64)
        ad += (double)xr[kk] * (double)wr[kk];
      #pragma unroll
      for (int dstep = 5; dstep >= 0; --dstep)
        ad += __shfl_xor(ad, 1 << dstep);
      if (lane == 0) {
        const double sd = 1.0 / (1.0 + exp(-ad));
        cand_sfc[c] = sd + (double)bg[e];
        cand_sv[c]  = sd;
      }
    }
    __syncthreads();
    if (wave == 0) {
      double gsd = -1e300;
      if (lane < NGRP) {
        double A = -1e300, B2 = -1e300;
        #pragma unroll
        for (int i = 0; i < 10; ++i) {
          const double v = cand_sfc[lane * 10 + i];
          if (v > A) { B2 = A; A = v; } else if (v > B2) { B2 = v; }
        }
        gsd = A + B2;
      }
      double gsvd[8];
      #pragma unroll
      for (int h = 0; h < 8; ++h) gsvd[h] = __shfl(gsd, h);
      int selm = 0;
      #pragma unroll
      for (int g = 0; g < 8; ++g) {
        int rank = 0;
        #pragma unroll
        for (int h = 0; h < 8; ++h)
          rank += (gsvd[h] > gsvd[g]) || ((gsvd[h] == gsvd[g]) && (h < g));
        if (rank < TOPKG) selm |= 1 << g;
      }
      const int cA = lane, cB = lane + 64;
      double vA = ((selm >> (cA / 10)) & 1) ? cand_sfc[cA] : -1e300;
      int eA = cand_id[cA];
      double vB = -1e300; int eB = 0x7FFFFFFF;
      if (cB < 80) {
        if ((selm >> (cB / 10)) & 1) vB = cand_sfc[cB];
        eB = cand_id[cB];
      }
      float wsum = 0.0f, mys = 0.0f; int myidx = 0;
      #pragma unroll
      for (int it = 0; it < KSEL; ++it) {
        double bv; int be, bc;
        if ((vB > vA) || ((vB == vA) && (eB < eA))) { bv = vB; be = eB; bc = cB; }
        else { bv = vA; be = eA; bc = cA; }
        #pragma unroll
        for (int dstep = 5; dstep >= 0; --dstep) {
          const int d = 1 << dstep;
          const double ov = __shfl_xor(bv, d);
          const int   oe = __shfl_xor(be, d);
          const int   oc = __shfl_xor(bc, d);
          if ((ov > bv) || ((ov == bv) && (oe < be))) { bv = ov; be = oe; bc = oc; }
        }
        const float sw = (float)cand_sv[bc];
        wsum += sw;
        if (lane == it) { myidx = be; mys = sw; }
        if (cA == bc) vA = -1e300;
        if (cB == bc) vB = -1e300;
      }
      if (lane < KSEL) {
        out[(size_t)(t0 + tk) * KSEL + lane] = (float)myidx;
        out[(size_t)NTOK * KSEL + (size_t)(t0 + tk) * KSEL + lane] =
            mys / (wsum + 1e-20f) * SCALE_F;
      }
    }
    __syncthreads();
  }
}

extern "C" void kernel_launch(void* const* d_in, const int* in_sizes, int n_in,
                              void* d_out, int out_size, void* d_ws, size_t ws_size,
                              hipStream_t stream) {
  (void)in_sizes; (void)n_in; (void)out_size;
  const float* xg = (const float*)d_in[0];
  const float* wg = (const float*)d_in[1];
  const float* bg = (const float*)d_in[2];
  float* out = (float*)d_out;

  const size_t need_t1 = PART8_BYTES + FLAG_BYTES + WPACK_BYTES;   // ~72 MB
  const size_t need_t2 = PART4_BYTES + FLAG_BYTES + WPACK_BYTES;   // ~40 MB
  const size_t need_t3 = PART4_BYTES + FLAG_BYTES;                 // ~32 MB

  if (ws_size >= need_t1) {
    // KS=8: 512 gemm blocks = 2/CU, ks == XCD id, wpack slice L2-resident
    float* part = (float*)d_ws;
    int* flaglist = (int*)((char*)d_ws + PART8_BYTES);
    unsigned short* wpack = (unsigned short*)((char*)d_ws + PART8_BYTES + FLAG_BYTES);
    hipLaunchKernelGGL(moe_wpack, dim3(NKT, 2), dim3(256), 0, stream, wg, wpack, flaglist);
    hipLaunchKernelGGL((moe_gemm_mfma<8>), dim3((NTOK / BT3) * 8), dim3(512), 0, stream,
                       xg, wpack, part);
    hipLaunchKernelGGL((moe_gate_from_part<8>), dim3(NTOK / BTG), dim3(256), 0, stream,
                       bg, part, flaglist, out, TAU_EMF, TAU_GMF);
    hipLaunchKernelGGL((moe_refine<8>), dim3(256), dim3(256), 0, stream,
                       xg, wg, bg, part, flaglist, out);
  } else if (ws_size >= need_t2) {
    // KS=4: exact round-6 verified config (148 us gemm)
    float* part = (float*)d_ws;
    int* flaglist = (int*)((char*)d_ws + PART4_BYTES);
    unsigned short* wpack = (unsigned short*)((char*)d_ws + PART4_BYTES + FLAG_BYTES);
    hipLaunchKernelGGL(moe_wpack, dim3(NKT, 2), dim3(256), 0, stream, wg, wpack, flaglist);
    hipLaunchKernelGGL((moe_gemm_mfma<4>), dim3((NTOK / BT3) * 4), dim3(512), 0, stream,
                       xg, wpack, part);
    hipLaunchKernelGGL((moe_gate_from_part<4>), dim3(NTOK / BTG), dim3(256), 0, stream,
                       bg, part, flaglist, out, TAU_EMF, TAU_GMF);
    hipLaunchKernelGGL((moe_refine<4>), dim3(256), dim3(256), 0, stream,
                       xg, wg, bg, part, flaglist, out);
  } else if (ws_size >= need_t3) {
    float* part = (float*)d_ws;
    int* flaglist = (int*)((char*)d_ws + PART4_BYTES);
    hipLaunchKernelGGL(moe_gemm_part, dim3(NTOK / BT2, KS4), dim3(256), 0, stream,
                       xg, wg, part, flaglist);
    hipLaunchKernelGGL((moe_gate_from_part<4>), dim3(NTOK / BTG), dim3(256), 0, stream,
                       bg, part, flaglist, out, TAU_E32, TAU_G32);
    hipLaunchKernelGGL((moe_refine<4>), dim3(256), dim3(256), 0, stream,
                       xg, wg, bg, part, flaglist, out);
  } else {
    hipLaunchKernelGGL(moe_gate_fused, dim3(NTOK / BT), dim3(NTHR), 0, stream,
                       xg, wg, bg, out);
  }
}

// Round 9
// 230.926 us; speedup vs baseline: 2.5188x; 2.5188x over previous
//
#include <hip/hip_runtime.h>
#include <math.h>

#define H_DIM 7168
#define NEXP  256
#define NGRP  8
#define EPG   32
#define TOPKG 4
#define KSEL  8
#define NTOK  8192
#define SCALE_F 2.5f

#define TAU_E32 3.0e-6f
#define TAU_G32 6.0e-6f
#define TAU_EMF 3.0e-5f
#define TAU_GMF 5.0e-5f

#define BT3   128                 // tokens per mfma block
#define NKT   (H_DIM / 32)        // 224 k-tiles total

// fp32 fallback GEMM config (KS=4)
#define KS4   4
#define KSPAN4 (H_DIM / KS4)      // 1792
#define BT2   64
#define BK2   16
#define NT2   (KSPAN4 / BK2)      // 112

// fused fallback config
#define BT    32
#define BK    16
#define NTILE (H_DIM / BK)
#define NTHR  256

#define BTG   16

#define PART4_BYTES ((size_t)4 * NTOK * NEXP * sizeof(float))   // 32 MB
#define PART8_BYTES ((size_t)8 * NTOK * NEXP * sizeof(float))   // 64 MB
#define FLAG_BYTES ((size_t)(((1 + NTOK) * 4 + 127) / 128) * 128)
#define WPACK_BYTES ((size_t)NKT * 32768)

typedef float f4v __attribute__((ext_vector_type(4)));
typedef short bf16x8 __attribute__((ext_vector_type(8)));
typedef float f32x16 __attribute__((ext_vector_type(16)));

__device__ __forceinline__ void gload16(const void* g, void* l) {
  __builtin_amdgcn_global_load_lds((const __attribute__((address_space(1))) unsigned int*)g,
                                   (__attribute__((address_space(3))) unsigned int*)l,
                                   16, 0, 0);
}

__device__ __forceinline__ void bf16split(float x, unsigned short& h, unsigned short& l) {
  unsigned int u  = __float_as_uint(x);
  unsigned int r  = u + 0x7FFFu + ((u >> 16) & 1u);      // RNE to bf16
  h = (unsigned short)(r >> 16);
  float hf = __uint_as_float(r & 0xFFFF0000u);
  float lo = x - hf;                                      // exact
  unsigned int ul = __float_as_uint(lo);
  unsigned int rl = ul + 0x7FFFu + ((ul >> 16) & 1u);
  l = (unsigned short)(rl >> 16);
}

__device__ __forceinline__ void split8(const f4v f0, const f4v f1, bf16x8& h8, bf16x8& l8) {
  #pragma unroll
  for (int j = 0; j < 8; ++j) {
    const float x = (j < 4) ? f0[j] : f1[j - 4];
    unsigned short hh, ll;
    bf16split(x, hh, ll);
    h8[j] = (short)hh;
    l8[j] = (short)ll;
  }
}

// ============================================================================
// W pre-pack: fragment-ordered bf16 hi/lo slabs (layout VERIFIED rounds 4-8).
// ============================================================================
__global__ __launch_bounds__(256)
void moe_wpack(const float* __restrict__ wg, unsigned short* __restrict__ wpack,
               int* __restrict__ flaglist) {
  if (blockIdx.x == 0 && blockIdx.y == 0 && threadIdx.x == 0) flaglist[0] = 0;
  const int kt   = blockIdx.x;
  const int half = blockIdx.y;
  const int tid  = threadIdx.x;
  #pragma unroll
  for (int i = 0; i < 4; ++i) {
    const int u    = tid + 256 * (4 * half + i);
    const int slab = u >> 6;
    const int lane = u & 63;
    const int d    = slab & 1;
    const int subK = (slab >> 1) & 1;
    const int expCg = slab >> 2;
    const int e = expCg * 32 + (lane & 31);
    const int k = kt * 32 + subK * 16 + (lane >> 5) * 8;
    const float* src = wg + (size_t)e * H_DIM + k;
    const f4v f0 = *(const f4v*)(src);
    const f4v f1 = *(const f4v*)(src + 4);
    bf16x8 o;
    #pragma unroll
    for (int j = 0; j < 8; ++j) {
      const float x = (j < 4) ? f0[j] : f1[j - 4];
      unsigned short hh, ll;
      bf16split(x, hh, ll);
      o[j] = (short)(d ? ll : hh);
    }
    *(bf16x8*)(wpack + (size_t)kt * 16384 + slab * 512 + lane * 8) = o;
  }
}

// ============================================================================
// Tier-1 GEMM (round 9): r6 body with SINGLE-buffered B registers so unified
// VGPR+AGPR fits <=128/wave -> 2 blocks/CU at grid 512 (KS=8, ks = XCD id).
// Compiled at (512,2): if regs overflow 128, worst case 1 blk/CU (= r6 perf),
// NO spill cliff.  A staged by all 512 threads (8 floats each).
// ============================================================================
__global__ __launch_bounds__(512, 2)
void moe_gemm_mfma8(const float* __restrict__ xg,
                    const unsigned short* __restrict__ wpack,
                    float* __restrict__ part) {
  constexpr int KSPANX = H_DIM / 8;    // 896
  constexpr int NT3X   = KSPANX / 32;  // 28
  __shared__ __align__(16) unsigned short a_sl[2][16][512];   // 32 KB

  const int tid  = threadIdx.x;
  const int lane = tid & 63;
  const int wv   = tid >> 6;
  const int tokG = wv >> 2;
  const int expG = wv & 3;

  const int bid  = blockIdx.x;
  const int ks   = bid & 7;           // == XCD id: wpack slice (1.8MB) L2-warm
  const int tokb = bid >> 3;          // 0..63
  const int t0   = tokb * BT3;
  const int kbase = ks * KSPANX;

  // A staging: all threads, 8 floats each. unit=(arow,asub,ahalf)
  const int arow = tid >> 2;          // 0..127
  const int asub = (tid >> 1) & 1;
  const int ahalf = tid & 1;
  const int arg  = arow >> 5;         // 0..3
  const int ar   = arow & 31;
  const int sh   = (arg * 2 + asub) * 2;      // hi slab; lo = sh+1
  const int apos = ar + ahalf * 32;           // r6 layout: k 0..7 -> ar, k 8..15 -> ar+32
  const float* axp = xg + (size_t)(t0 + arow) * H_DIM + kbase + asub * 16 + ahalf * 8;

  f32x16 acc[2][2];
  #pragma unroll
  for (int tc = 0; tc < 2; ++tc)
    #pragma unroll
    for (int ec = 0; ec < 2; ++ec)
      #pragma unroll
      for (int r = 0; r < 16; ++r) acc[tc][ec][r] = 0.0f;

  f4v xr0, xr1;
  auto loadX = [&](int t) {
    const float* p = axp + t * 32;
    xr0 = *(const f4v*)(p);
    xr1 = *(const f4v*)(p + 4);
  };
  auto writeA = [&](int buf) {
    bf16x8 h8, l8;
    split8(xr0, xr1, h8, l8);
    *(bf16x8*)&a_sl[buf][sh][apos * 8]     = h8;
    *(bf16x8*)&a_sl[buf][sh + 1][apos * 8] = l8;
  };
  auto loadB = [&](int t, bf16x8 (&B)[2][2][2]) {
    const unsigned short* bp = wpack + (size_t)(ks * NT3X + t) * 16384 + lane * 8;
    #pragma unroll
    for (int s = 0; s < 2; ++s)
      #pragma unroll
      for (int ec = 0; ec < 2; ++ec)
        #pragma unroll
        for (int d = 0; d < 2; ++d)
          B[s][ec][d] = *(const bf16x8*)(bp + (size_t)((((expG * 2 + ec) * 2 + s) * 2 + d) * 512));
  };
  auto compute = [&](int buf, bf16x8 (&B)[2][2][2]) {
    #pragma unroll
    for (int s = 0; s < 2; ++s) {
      bf16x8 ah2[2], al2[2];
      #pragma unroll
      for (int tc = 0; tc < 2; ++tc) {
        const int sa = ((tokG * 2 + tc) * 2 + s) * 2;
        ah2[tc] = *(const bf16x8*)&a_sl[buf][sa][lane * 8];
        al2[tc] = *(const bf16x8*)&a_sl[buf][sa + 1][lane * 8];
      }
      #pragma unroll
      for (int tc = 0; tc < 2; ++tc)
        #pragma unroll
        for (int ec = 0; ec < 2; ++ec) {
          acc[tc][ec] = __builtin_amdgcn_mfma_f32_32x32x16_bf16(ah2[tc], B[s][ec][0], acc[tc][ec], 0, 0, 0);
          acc[tc][ec] = __builtin_amdgcn_mfma_f32_32x32x16_bf16(ah2[tc], B[s][ec][1], acc[tc][ec], 0, 0, 0);
          acc[tc][ec] = __builtin_amdgcn_mfma_f32_32x32x16_bf16(al2[tc], B[s][ec][0], acc[tc][ec], 0, 0, 0);
        }
    }
  };

  bf16x8 B[2][2][2];
  loadX(0);
  loadB(0, B);
  writeA(0);
  asm volatile("s_waitcnt lgkmcnt(0)\n\ts_barrier" ::: "memory");

  #pragma unroll 1
  for (int t = 0; t < NT3X; ++t) {
    const bool more = (t + 1 < NT3X);
    if (more) loadX(t + 1);       // x load issues early; latency under compute
    compute(t & 1, B);            // consumes B(t); WAR lets loadB follow
    if (more) {
      loadB(t + 1, B);            // single-buffer refill; latency hidden by TLP
      writeA((t + 1) & 1);
    }
    asm volatile("s_waitcnt lgkmcnt(0)\n\ts_barrier" ::: "memory");
  }

  // epilogue: C/D layout col=lane&31 (expert), row=(reg&3)+8*(reg>>2)+4*(lane>>5)
  #pragma unroll
  for (int tc = 0; tc < 2; ++tc)
    #pragma unroll
    for (int ec = 0; ec < 2; ++ec)
      #pragma unroll
      for (int reg = 0; reg < 16; ++reg) {
        const int row = (reg & 3) + 8 * (reg >> 2) + 4 * (lane >> 5);
        const int tok = t0 + tokG * 64 + tc * 32 + row;
        const int e   = expG * 64 + ec * 32 + (lane & 31);
        part[((size_t)ks * NTOK + tok) * NEXP + e] = acc[tc][ec][reg];
      }
}

// ============================================================================
// Tier-2 GEMM: EXACT round-6 kernel (148 us verified), KS=4, grid 256,
// launch_bounds(512,2) restored (r8's template had wrongly used (512,4)).
// ============================================================================
__global__ __launch_bounds__(512, 2)
void moe_gemm_mfma4(const float* __restrict__ xg,
                    const unsigned short* __restrict__ wpack,
                    float* __restrict__ part) {
  constexpr int KSPANX = H_DIM / 4;    // 1792
  constexpr int NT3X   = KSPANX / 32;  // 56
  __shared__ __align__(16) unsigned short a_sl[2][16][512];   // 32 KB

  const int tid  = threadIdx.x;
  const int lane = tid & 63;
  const int wv   = tid >> 6;
  const int tokG = wv >> 2;
  const int expG = wv & 3;

  const int bid  = blockIdx.x;
  const int ks   = (bid & 7) >> 1;
  const int tokb = ((bid >> 3) << 1) | (bid & 1);
  const int t0   = tokb * BT3;
  const int kbase = ks * KSPANX;

  const bool stg = (tid & 1) == 0;
  const int arow = tid >> 2;
  const int asub = (tid >> 1) & 1;
  const int arg  = arow >> 5;
  const int ar   = arow & 31;
  const int sh   = (arg * 2 + asub) * 2;
  const float* axp = xg + (size_t)(t0 + arow) * H_DIM + kbase + asub * 16;

  f32x16 acc[2][2];
  #pragma unroll
  for (int tc = 0; tc < 2; ++tc)
    #pragma unroll
    for (int ec = 0; ec < 2; ++ec)
      #pragma unroll
      for (int r = 0; r < 16; ++r) acc[tc][ec][r] = 0.0f;

  f4v xr0, xr1, yr0, yr1;
  auto loadX2 = [&](int t) {
    if (!stg) return;
    const float* p = axp + t * 32;
    xr0 = *(const f4v*)(p);
    xr1 = *(const f4v*)(p + 4);
    yr0 = *(const f4v*)(p + 8);
    yr1 = *(const f4v*)(p + 12);
  };
  auto writeA2 = [&](int buf) {
    if (!stg) return;
    bf16x8 h0, l0, h1, l1;
    split8(xr0, xr1, h0, l0);
    split8(yr0, yr1, h1, l1);
    *(bf16x8*)&a_sl[buf][sh][ar * 8]            = h0;
    *(bf16x8*)&a_sl[buf][sh][(32 + ar) * 8]     = h1;
    *(bf16x8*)&a_sl[buf][sh + 1][ar * 8]        = l0;
    *(bf16x8*)&a_sl[buf][sh + 1][(32 + ar) * 8] = l1;
  };
  auto loadB = [&](int t, bf16x8 (&B)[2][2][2]) {
    const unsigned short* bp = wpack + (size_t)(ks * NT3X + t) * 16384 + lane * 8;
    #pragma unroll
    for (int s = 0; s < 2; ++s)
      #pragma unroll
      for (int ec = 0; ec < 2; ++ec)
        #pragma unroll
        for (int d = 0; d < 2; ++d)
          B[s][ec][d] = *(const bf16x8*)(bp + (size_t)((((expG * 2 + ec) * 2 + s) * 2 + d) * 512));
  };
  auto compute = [&](int buf, bf16x8 (&B)[2][2][2]) {
    #pragma unroll
    for (int s = 0; s < 2; ++s) {
      bf16x8 ah2[2], al2[2];
      #pragma unroll
      for (int tc = 0; tc < 2; ++tc) {
        const int sa = ((tokG * 2 + tc) * 2 + s) * 2;
        ah2[tc] = *(const bf16x8*)&a_sl[buf][sa][lane * 8];
        al2[tc] = *(const bf16x8*)&a_sl[buf][sa + 1][lane * 8];
      }
      #pragma unroll
      for (int tc = 0; tc < 2; ++tc)
        #pragma unroll
        for (int ec = 0; ec < 2; ++ec) {
          acc[tc][ec] = __builtin_amdgcn_mfma_f32_32x32x16_bf16(ah2[tc], B[s][ec][0], acc[tc][ec], 0, 0, 0);
          acc[tc][ec] = __builtin_amdgcn_mfma_f32_32x32x16_bf16(ah2[tc], B[s][ec][1], acc[tc][ec], 0, 0, 0);
          acc[tc][ec] = __builtin_amdgcn_mfma_f32_32x32x16_bf16(al2[tc], B[s][ec][0], acc[tc][ec], 0, 0, 0);
        }
    }
  };

  bf16x8 BA[2][2][2], BB[2][2][2];
  loadX2(0);
  loadB(0, BA);
  writeA2(0);
  asm volatile("s_waitcnt lgkmcnt(0)\n\ts_barrier" ::: "memory");

  #pragma unroll 1
  for (int k = 0; k < NT3X / 2; ++k) {
    const int t = 2 * k;
    loadX2(t + 1);
    loadB(t + 1, BB);
    compute(0, BA);
    writeA2(1);
    asm volatile("s_waitcnt lgkmcnt(0)\n\ts_barrier" ::: "memory");
    const bool more = (t + 2 < NT3X);
    if (more) { loadX2(t + 2); loadB(t + 2, BA); }
    compute(1, BB);
    if (more) writeA2(0);
    asm volatile("s_waitcnt lgkmcnt(0)\n\ts_barrier" ::: "memory");
  }

  #pragma unroll
  for (int tc = 0; tc < 2; ++tc)
    #pragma unroll
    for (int ec = 0; ec < 2; ++ec)
      #pragma unroll
      for (int reg = 0; reg < 16; ++reg) {
        const int row = (reg & 3) + 8 * (reg >> 2) + 4 * (lane >> 5);
        const int tok = t0 + tokG * 64 + tc * 32 + row;
        const int e   = expG * 64 + ec * 32 + (lane & 31);
        part[((size_t)ks * NTOK + tok) * NEXP + e] = acc[tc][ec][reg];
      }
}

// ============================================================================
// fp32 fallback GEMM (round-3 verified).
// ============================================================================
__global__ __launch_bounds__(256, 2)
void moe_gemm_part(const float* __restrict__ xg,
                   const float* __restrict__ wg,
                   float* __restrict__ part,
                   int* __restrict__ flaglist) {
  __shared__ __align__(16) float w_t[2][4][NEXP][4];
  __shared__ __align__(16) float x_t[2][4][BT2][4];

  if (blockIdx.x == 0 && blockIdx.y == 0 && threadIdx.x == 0) flaglist[0] = 0;

  const int tid  = threadIdx.x;
  const int lane = tid & 63;
  const int wave = tid >> 6;
  const int c32  = lane & 31;
  const int tb   = (wave << 1) | (lane >> 5);
  const int t0   = blockIdx.x * BT2;
  const int ks   = blockIdx.y;
  const int kbase = ks * KSPAN4;

  float acc[8][8];
  #pragma unroll
  for (int i = 0; i < 8; ++i)
    #pragma unroll
    for (int j = 0; j < 8; ++j) acc[i][j] = 0.0f;

  auto stage = [&](int b, int t) {
    const int k0 = kbase + t * BK2;
    #pragma unroll
    for (int h = 0; h < 4; ++h)
      gload16(wg + (size_t)(h * 64 + lane) * H_DIM + k0 + 4 * wave,
              &w_t[b][wave][h * 64][0]);
    gload16(xg + (size_t)(t0 + lane) * H_DIM + k0 + 4 * wave, &x_t[b][wave][0][0]);
  };

  auto compute = [&](int b) {
    float accp[8][8];
    #pragma unroll
    for (int i = 0; i < 8; ++i)
      #pragma unroll
      for (int j = 0; j < 8; ++j) accp[i][j] = 0.0f;
    #pragma unroll
    for (int kq = 0; kq < 4; ++kq) {
      f4v wf[8], xf[8];
      #pragma unroll
      for (int j = 0; j < 8; ++j) wf[j] = *(const f4v*)&w_t[b][kq][c32 + 32 * j][0];
      #pragma unroll
      for (int i = 0; i < 8; ++i) xf[i] = *(const f4v*)&x_t[b][kq][tb * 8 + i][0];
      #pragma unroll
      for (int i = 0; i < 8; ++i)
        #pragma unroll
        for (int j = 0; j < 8; ++j) {
          accp[i][j] = fmaf(xf[i][0], wf[j][0], accp[i][j]);
          accp[i][j] = fmaf(xf[i][1], wf[j][1], accp[i][j]);
          accp[i][j] = fmaf(xf[i][2], wf[j][2], accp[i][j]);
          accp[i][j] = fmaf(xf[i][3], wf[j][3], accp[i][j]);
        }
    }
    #pragma unroll
    for (int i = 0; i < 8; ++i)
      #pragma unroll
      for (int j = 0; j < 8; ++j) acc[i][j] += accp[i][j];
  };

  stage(0, 0);
  __syncthreads();
  for (int t = 0; t < NT2; ++t) {
    const int cur = t & 1;
    if (t + 1 < NT2) stage(cur ^ 1, t + 1);
    compute(cur);
    __syncthreads();
  }

  float* pp = part + ((size_t)ks * NTOK + t0) * NEXP;
  #pragma unroll
  for (int i = 0; i < 8; ++i)
    #pragma unroll
    for (int j = 0; j < 8; ++j)
      pp[(size_t)(tb * 8 + i) * NEXP + c32 + 32 * j] = acc[i][j];
}

// ============================================================================
// Phase 2: sum KSX partials -> gating; flagged tokens -> flaglist.
// ============================================================================
template <int KSX>
__global__ __launch_bounds__(256, 2)
void moe_gate_from_part(const float* __restrict__ bg,
                        const float* __restrict__ part,
                        int* __restrict__ flaglist,
                        float* __restrict__ out,
                        float tauE, float tauG) {
  __shared__ __align__(16) float logits[BTG * NEXP];

  const int tid  = threadIdx.x;
  const int lane = tid & 63;
  const int wave = tid >> 6;
  const int t0   = blockIdx.x * BTG;

  #pragma unroll
  for (int m = 0; m < (BTG * 64) / 256; ++m) {
    const int idx = tid + 256 * m;
    const int tt  = idx >> 6;
    const int ch  = idx & 63;
    f4v s;
    s[0] = 0.f; s[1] = 0.f; s[2] = 0.f; s[3] = 0.f;
    #pragma unroll
    for (int sp = 0; sp < KSX; ++sp) {
      const f4v v = *(const f4v*)&part[(((size_t)sp * NTOK) + t0 + tt) * NEXP + 4 * ch];
      s[0] += v[0]; s[1] += v[1]; s[2] += v[2]; s[3] += v[3];
    }
    *(f4v*)&logits[tt * NEXP + 4 * ch] = s;
  }
  __syncthreads();

  const f4v bias4 = *(const f4v*)(bg + 4 * lane);

  for (int tk = wave; tk < BTG; tk += 4) {
    const float* lrow = logits + tk * NEXP;
    const f4v lz = *(const f4v*)&lrow[4 * lane];
    float sc[4], vc[4];
    #pragma unroll
    for (int j = 0; j < 4; ++j) {
      sc[j] = 1.0f / (1.0f + expf(-lz[j]));
      vc[j] = sc[j] + bias4[j];
    }
    float a1 = -INFINITY, a2 = -INFINITY;
    #pragma unroll
    for (int j = 0; j < 4; ++j) {
      const float v = vc[j];
      if (v > a1) { a2 = a1; a1 = v; } else if (v > a2) { a2 = v; }
    }
    #pragma unroll
    for (int dstep = 0; dstep < 3; ++dstep) {
      const int d = 1 << dstep;
      const float o1 = __shfl_xor(a1, d);
      const float o2 = __shfl_xor(a2, d);
      if (o1 > a1) { a2 = fmaxf(a1, o2); a1 = o1; }
      else         { a2 = fmaxf(a2, o1); }
    }
    const float gs = a1 + a2;
    float gsv[8];
    #pragma unroll
    for (int h = 0; h < 8; ++h) gsv[h] = __shfl(gs, h * 8);
    int selmask = 0; float r4v = 0.0f, r5v = 0.0f;
    #pragma unroll
    for (int g = 0; g < 8; ++g) {
      int rank = 0;
      #pragma unroll
      for (int h = 0; h < 8; ++h)
        rank += (gsv[h] > gsv[g]) || ((gsv[h] == gsv[g]) && (h < g));
      if (rank < TOPKG) selmask |= 1 << g;
      if (rank == TOPKG - 1) r4v = gsv[g];
      if (rank == TOPKG)     r5v = gsv[g];
    }
    const bool msel = (selmask >> (lane >> 3)) & 1;
    float mv[4];
    #pragma unroll
    for (int j = 0; j < 4; ++j) mv[j] = msel ? vc[j] : -INFINITY;

    int rem = 0xF;
    float wsum = 0.0f, mys = 0.0f, prev = 0.0f, minm = 1e30f;
    int myidx = 0;
    #pragma unroll
    for (int it = 0; it < KSEL + 1; ++it) {
      float bv = -INFINITY, bs = 0.0f; int bi = 0x7FFFFFFF;
      #pragma unroll
      for (int j = 0; j < 4; ++j)
        if ((rem >> j) & 1) {
          if (mv[j] > bv) { bv = mv[j]; bs = sc[j]; bi = 4 * lane + j; }
        }
      #pragma unroll
      for (int dstep = 5; dstep >= 0; --dstep) {
        const int d = 1 << dstep;
        const float ov = __shfl_xor(bv, d);
        const float os = __shfl_xor(bs, d);
        const int   oi = __shfl_xor(bi, d);
        if ((ov > bv) || ((ov == bv) && (oi < bi))) { bv = ov; bs = os; bi = oi; }
      }
      if (it > 0) minm = fminf(minm, prev - bv);
      prev = bv;
      if (it < KSEL) {
        wsum += bs;
        if (lane == it) { myidx = bi; mys = bs; }
        if ((bi >> 2) == lane) rem &= ~(1 << (bi & 3));
      }
    }
    const bool flagged = (minm < tauE) || ((r4v - r5v) < tauG);
    if (flagged) {
      if (lane == 0) {
        const int p = atomicAdd(&flaglist[0], 1);
        flaglist[1 + p] = t0 + tk;
      }
    } else if (lane < KSEL) {
      out[(size_t)(t0 + tk) * KSEL + lane] = (float)myidx;
      out[(size_t)NTOK * KSEL + (size_t)(t0 + tk) * KSEL + lane] =
          mys / (wsum + 1e-20f) * SCALE_F;
    }
  }
}

// ============================================================================
// Phase 3: f64 refine, one block per flagged token, 2-way ILP dots.
// Round 9: grid 1024 (flag count can exceed 256).
// ============================================================================
template <int KSX>
__global__ __launch_bounds__(256, 2)
void moe_refine(const float* __restrict__ xg,
                const float* __restrict__ wg,
                const float* __restrict__ bg,
                const float* __restrict__ part,
                const int* __restrict__ flaglist,
                float* __restrict__ out) {
  __shared__ __align__(16) float xrow[H_DIM];
  __shared__ float  sfc32[NEXP];
  __shared__ int    cand_id[80];
  __shared__ double cand_sfc[80];
  __shared__ double cand_sv[80];

  const int tid  = threadIdx.x;
  const int lane = tid & 63;
  const int wave = tid >> 6;
  const int count = flaglist[0];

  for (int item = blockIdx.x; item < count; item += gridDim.x) {
    const int tok = flaglist[1 + item];

    {
      float lg = 0.0f;
      #pragma unroll
      for (int sp = 0; sp < KSX; ++sp)
        lg += part[((size_t)sp * NTOK + tok) * NEXP + tid];
      sfc32[tid] = 1.0f / (1.0f + expf(-lg)) + bg[tid];
    }
    for (int i = tid; i < H_DIM / 4; i += 256)
      *(f4v*)&xrow[4 * i] = *(const f4v*)&xg[(size_t)tok * H_DIM + 4 * i];
    __syncthreads();

    {
      const int g  = 2 * wave + (lane >> 5);
      const int el = lane & 31;
      const int e  = g * EPG + el;
      float vv = sfc32[e];
      #pragma unroll 1
      for (int it = 0; it < 10; ++it) {
        float bv = vv; int bi = e;
        #pragma unroll
        for (int dstep = 4; dstep >= 0; --dstep) {
          const int d = 1 << dstep;
          const float ov = __shfl_xor(bv, d);
          const int   oi = __shfl_xor(bi, d);
          if ((ov > bv) || ((ov == bv) && (oi < bi))) { bv = ov; bi = oi; }
        }
        if (el == 0) cand_id[g * 10 + it] = bi;
        if (e == bi) vv = -INFINITY;
      }
    }
    __syncthreads();

    #pragma unroll 1
    for (int cc = wave; cc < 40; cc += 4) {
      const int c1 = cc, c2 = cc + 40;
      const int e1 = cand_id[c1], e2 = cand_id[c2];
      const float* w1 = wg + (size_t)e1 * H_DIM;
      const float* w2 = wg + (size_t)e2 * H_DIM;
      double a1[4], a2d[4];
      #pragma unroll
      for (int r = 0; r < 4; ++r) { a1[r] = 0.0; a2d[r] = 0.0; }
      #pragma unroll 1
      for (int base = 0; base < H_DIM; base += 256) {
        #pragma unroll
        for (int r = 0; r < 4; ++r) {
          const int kk = base + 64 * r + lane;
          const double xv = (double)xrow[kk];
          a1[r]  = fma(xv, (double)w1[kk], a1[r]);
          a2d[r] = fma(xv, (double)w2[kk], a2d[r]);
        }
      }
      double s1 = (a1[0] + a1[1]) + (a1[2] + a1[3]);
      double s2 = (a2d[0] + a2d[1]) + (a2d[2] + a2d[3]);
      #pragma unroll
      for (int dstep = 5; dstep >= 0; --dstep) {
        s1 += __shfl_xor(s1, 1 << dstep);
        s2 += __shfl_xor(s2, 1 << dstep);
      }
      if (lane == 0) {
        const double sd1 = 1.0 / (1.0 + exp(-s1));
        const double sd2 = 1.0 / (1.0 + exp(-s2));
        cand_sfc[c1] = sd1 + (double)bg[e1];  cand_sv[c1] = sd1;
        cand_sfc[c2] = sd2 + (double)bg[e2];  cand_sv[c2] = sd2;
      }
    }
    __syncthreads();

    if (wave == 0) {
      double gsd = -1e300;
      if (lane < NGRP) {
        double A = -1e300, B2 = -1e300;
        #pragma unroll
        for (int i = 0; i < 10; ++i) {
          const double v = cand_sfc[lane * 10 + i];
          if (v > A) { B2 = A; A = v; } else if (v > B2) { B2 = v; }
        }
        gsd = A + B2;
      }
      double gsvd[8];
      #pragma unroll
      for (int h = 0; h < 8; ++h) gsvd[h] = __shfl(gsd, h);
      int selm = 0;
      #pragma unroll
      for (int g = 0; g < 8; ++g) {
        int rank = 0;
        #pragma unroll
        for (int h = 0; h < 8; ++h)
          rank += (gsvd[h] > gsvd[g]) || ((gsvd[h] == gsvd[g]) && (h < g));
        if (rank < TOPKG) selm |= 1 << g;
      }
      const int cA = lane, cB = lane + 64;
      double vA = ((selm >> (cA / 10)) & 1) ? cand_sfc[cA] : -1e300;
      int eA = cand_id[cA];
      double vB = -1e300; int eB = 0x7FFFFFFF;
      if (cB < 80) {
        if ((selm >> (cB / 10)) & 1) vB = cand_sfc[cB];
        eB = cand_id[cB];
      }
      float wsum = 0.0f, mys = 0.0f; int myidx = 0;
      #pragma unroll
      for (int it = 0; it < KSEL; ++it) {
        double bv; int be, bc;
        if ((vB > vA) || ((vB == vA) && (eB < eA))) { bv = vB; be = eB; bc = cB; }
        else { bv = vA; be = eA; bc = cA; }
        #pragma unroll
        for (int dstep = 5; dstep >= 0; --dstep) {
          const int d = 1 << dstep;
          const double ov = __shfl_xor(bv, d);
          const int   oe = __shfl_xor(be, d);
          const int   oc = __shfl_xor(bc, d);
          if ((ov > bv) || ((ov == bv) && (oe < be))) { bv = ov; be = oe; bc = oc; }
        }
        const float sw = (float)cand_sv[bc];
        wsum += sw;
        if (lane == it) { myidx = be; mys = sw; }
        if (cA == bc) vA = -1e300;
        if (cB == bc) vB = -1e300;
      }
      if (lane < KSEL) {
        out[(size_t)tok * KSEL + lane] = (float)myidx;
        out[(size_t)NTOK * KSEL + (size_t)tok * KSEL + lane] =
            mys / (wsum + 1e-20f) * SCALE_F;
      }
    }
    __syncthreads();
  }
}

// ============================================================================
// Full fused fallback (round-1 verified) — used only if ws is tiny.
// ============================================================================
__global__ __launch_bounds__(NTHR, 1)
void moe_gate_fused(const float* __restrict__ xg,
                    const float* __restrict__ wg,
                    const float* __restrict__ bg,
                    float* __restrict__ out) {
  __shared__ __align__(16) float lds_w[2][BK * NEXP];
  __shared__ __align__(16) float lds_x[2][BK * BT];
  __shared__ int    lds_flag[BT];
  __shared__ int    cand_id[80];
  __shared__ double cand_sfc[80];
  __shared__ double cand_sv[80];

  const int tid  = threadIdx.x;
  const int lane = tid & 63;
  const int wave = tid >> 6;
  const int er   = tid & 63;
  const int tr   = tid >> 6;
  const int t0   = blockIdx.x * BT;
  const int wkq = tid & 3;
  const int wet = tid >> 2;
  const int xkq = tid & 3;
  const int xtq = tid >> 2;

  float acc[8][4];
  #pragma unroll
  for (int i = 0; i < 8; ++i)
    #pragma unroll
    for (int j = 0; j < 4; ++j) acc[i][j] = 0.0f;

  const f4v bias4 = *(const f4v*)(bg + 4 * lane);
  f4v wv[4];
  f4v xv;

  auto load_tile = [&](int t) {
    const int k0 = t * BK;
    const float* wp = wg + (size_t)wet * H_DIM + k0 + 4 * wkq;
    wv[0] = *(const f4v*)(wp);
    wv[1] = *(const f4v*)(wp + (size_t)64  * H_DIM);
    wv[2] = *(const f4v*)(wp + (size_t)128 * H_DIM);
    wv[3] = *(const f4v*)(wp + (size_t)192 * H_DIM);
    if (tid < 128)
      xv = *(const f4v*)(xg + (size_t)(t0 + xtq) * H_DIM + k0 + 4 * xkq);
  };

  auto stage_tile = [&](int b) {
    #pragma unroll
    for (int p = 0; p < 4; ++p) {
      const int e = 64 * p + wet;
      const int g = e >> 2, r = e & 3;
      #pragma unroll
      for (int j = 0; j < 4; ++j) {
        const int k = 4 * wkq + j;
        lds_w[b][k * NEXP + 4 * (g ^ wkq) + r] = wv[p][j];
      }
    }
    if (tid < 128) {
      #pragma unroll
      for (int j = 0; j < 4; ++j) {
        const int k = 4 * xkq + j;
        lds_x[b][k * BT + (xtq ^ (xkq << 3))] = xv[j];
      }
    }
  };

  auto compute_tile = [&](int b) {
    float accp[8][4];
    #pragma unroll
    for (int i = 0; i < 8; ++i)
      #pragma unroll
      for (int j = 0; j < 4; ++j) accp[i][j] = 0.0f;
    #pragma unroll
    for (int k = 0; k < BK; ++k) {
      const int kq = k >> 2;
      const f4v wf  = *(const f4v*)&lds_w[b][k * NEXP + 4 * (er ^ kq)];
      const int xb  = k * BT + 8 * (tr ^ kq);
      const f4v xf0 = *(const f4v*)&lds_x[b][xb];
      const f4v xf1 = *(const f4v*)&lds_x[b][xb + 4];
      #pragma unroll
      for (int i = 0; i < 4; ++i)
        #pragma unroll
        for (int j = 0; j < 4; ++j) {
          accp[i][j]     = fmaf(xf0[i], wf[j], accp[i][j]);
          accp[i + 4][j] = fmaf(xf1[i], wf[j], accp[i + 4][j]);
        }
    }
    #pragma unroll
    for (int i = 0; i < 8; ++i)
      #pragma unroll
      for (int j = 0; j < 4; ++j) acc[i][j] += accp[i][j];
  };

  load_tile(0);
  stage_tile(0);
  __syncthreads();
  for (int t = 0; t < NTILE; ++t) {
    const int cur = t & 1;
    if (t + 1 < NTILE) load_tile(t + 1);
    compute_tile(cur);
    if (t + 1 < NTILE) stage_tile(cur ^ 1);
    __syncthreads();
  }

  float* logits = &lds_w[0][0];
  #pragma unroll
  for (int i = 0; i < 8; ++i) {
    f4v o;
    o[0] = acc[i][0]; o[1] = acc[i][1]; o[2] = acc[i][2]; o[3] = acc[i][3];
    *(f4v*)&logits[(8 * tr + i) * NEXP + 4 * er] = o;
  }
  if (tid < BT) lds_flag[tid] = 0;
  __syncthreads();

  for (int tk = wave; tk < BT; tk += 4) {
    const float* lrow = logits + tk * NEXP;
    const f4v lz = *(const f4v*)&lrow[4 * lane];
    float sc[4], vc[4];
    #pragma unroll
    for (int j = 0; j < 4; ++j) {
      sc[j] = 1.0f / (1.0f + expf(-lz[j]));
      vc[j] = sc[j] + bias4[j];
    }
    float a1 = -INFINITY, a2 = -INFINITY;
    #pragma unroll
    for (int j = 0; j < 4; ++j) {
      const float v = vc[j];
      if (v > a1) { a2 = a1; a1 = v; } else if (v > a2) { a2 = v; }
    }
    #pragma unroll
    for (int dstep = 0; dstep < 3; ++dstep) {
      const int d = 1 << dstep;
      const float o1 = __shfl_xor(a1, d);
      const float o2 = __shfl_xor(a2, d);
      if (o1 > a1) { a2 = fmaxf(a1, o2); a1 = o1; }
      else         { a2 = fmaxf(a2, o1); }
    }
    const float gs = a1 + a2;
    float gsv[8];
    #pragma unroll
    for (int h = 0; h < 8; ++h) gsv[h] = __shfl(gs, h * 8);
    int selmask = 0; float r4v = 0.0f, r5v = 0.0f;
    #pragma unroll
    for (int g = 0; g < 8; ++g) {
      int rank = 0;
      #pragma unroll
      for (int h = 0; h < 8; ++h)
        rank += (gsv[h] > gsv[g]) || ((gsv[h] == gsv[g]) && (h < g));
      if (rank < TOPKG) selmask |= 1 << g;
      if (rank == TOPKG - 1) r4v = gsv[g];
      if (rank == TOPKG)     r5v = gsv[g];
    }
    const bool msel = (selmask >> (lane >> 3)) & 1;
    float mv[4];
    #pragma unroll
    for (int j = 0; j < 4; ++j) mv[j] = msel ? vc[j] : -INFINITY;

    int rem = 0xF;
    float wsum = 0.0f, mys = 0.0f, prev = 0.0f, minm = 1e30f;
    int myidx = 0;
    #pragma unroll
    for (int it = 0; it < KSEL + 1; ++it) {
      float bv = -INFINITY, bs = 0.0f; int bi = 0x7FFFFFFF;
      #pragma unroll
      for (int j = 0; j < 4; ++j)
        if ((rem >> j) & 1) {
          if (mv[j] > bv) { bv = mv[j]; bs = sc[j]; bi = 4 * lane + j; }
        }
      #pragma unroll
      for (int dstep = 5; dstep >= 0; --dstep) {
        const int d = 1 << dstep;
        const float ov = __shfl_xor(bv, d);
        const float os = __shfl_xor(bs, d);
        const int   oi = __shfl_xor(bi, d);
        if ((ov > bv) || ((ov == bv) && (oi < bi))) { bv = ov; bs = os; bi = oi; }
      }
      if (it > 0) minm = fminf(minm, prev - bv);
      prev = bv;
      if (it < KSEL) {
        wsum += bs;
        if (lane == it) { myidx = bi; mys = bs; }
        if ((bi >> 2) == lane) rem &= ~(1 << (bi & 3));
      }
    }
    const bool flagged = (minm < TAU_E32) || ((r4v - r5v) < TAU_G32);
    if (flagged) {
      if (lane == 0) lds_flag[tk] = 1;
    } else if (lane < KSEL) {
      out[(size_t)(t0 + tk) * KSEL + lane] = (float)myidx;
      out[(size_t)NTOK * KSEL + (size_t)(t0 + tk) * KSEL + lane] =
          mys / (wsum + 1e-20f) * SCALE_F;
    }
  }
  __syncthreads();

  #pragma unroll 1
  for (int tk = 0; tk < BT; ++tk) {
    if (!lds_flag[tk]) continue;
    {
      const int g  = 2 * wave + (lane >> 5);
      const int el = lane & 31;
      const int e  = g * EPG + el;
      const float z = logits[tk * NEXP + e];
      float vv = 1.0f / (1.0f + expf(-z)) + bg[e];
      #pragma unroll 1
      for (int it = 0; it < 10; ++it) {
        float bv = vv; int bi = e;
        #pragma unroll
        for (int dstep = 4; dstep >= 0; --dstep) {
          const int d = 1 << dstep;
          const float ov = __shfl_xor(bv, d);
          const int   oi = __shfl_xor(bi, d);
          if ((ov > bv) || ((ov == bv) && (oi < bi))) { bv = ov; bi = oi; }
        }
        if (el == 0) cand_id[g * 10 + it] = bi;
        if (e == bi) vv = -INFINITY;
      }
    }
    __syncthreads();
    #pragma unroll 1
    for (int c = wave; c < 80; c += 4) {
      const int e = cand_id[c];
      const float* xr = xg + (size_t)(t0 + tk) * H_DIM;
      const float* wr = wg + (size_t)e * H_DIM;
      double ad = 0.0;
      for (int kk = lane; kk < H_DIM; kk += 64)
        ad += (double)xr[kk] * (double)wr[kk];
      #pragma unroll
      for (int dstep = 5; dstep >= 0; --dstep)
        ad += __shfl_xor(ad, 1 << dstep);
      if (lane == 0) {
        const double sd = 1.0 / (1.0 + exp(-ad));
        cand_sfc[c] = sd + (double)bg[e];
        cand_sv[c]  = sd;
      }
    }
    __syncthreads();
    if (wave == 0) {
      double gsd = -1e300;
      if (lane < NGRP) {
        double A = -1e300, B2 = -1e300;
        #pragma unroll
        for (int i = 0; i < 10; ++i) {
          const double v = cand_sfc[lane * 10 + i];
          if (v > A) { B2 = A; A = v; } else if (v > B2) { B2 = v; }
        }
        gsd = A + B2;
      }
      double gsvd[8];
      #pragma unroll
      for (int h = 0; h < 8; ++h) gsvd[h] = __shfl(gsd, h);
      int selm = 0;
      #pragma unroll
      for (int g = 0; g < 8; ++g) {
        int rank = 0;
        #pragma unroll
        for (int h = 0; h < 8; ++h)
          rank += (gsvd[h] > gsvd[g]) || ((gsvd[h] == gsvd[g]) && (h < g));
        if (rank < TOPKG) selm |= 1 << g;
      }
      const int cA = lane, cB = lane + 64;
      double vA = ((selm >> (cA / 10)) & 1) ? cand_sfc[cA] : -1e300;
      int eA = cand_id[cA];
      double vB = -1e300; int eB = 0x7FFFFFFF;
      if (cB < 80) {
        if ((selm >> (cB / 10)) & 1) vB = cand_sfc[cB];
        eB = cand_id[cB];
      }
      float wsum = 0.0f, mys = 0.0f; int myidx = 0;
      #pragma unroll
      for (int it = 0; it < KSEL; ++it) {
        double bv; int be, bc;
        if ((vB > vA) || ((vB == vA) && (eB < eA))) { bv = vB; be = eB; bc = cB; }
        else { bv = vA; be = eA; bc = cA; }
        #pragma unroll
        for (int dstep = 5; dstep >= 0; --dstep) {
          const int d = 1 << dstep;
          const double ov = __shfl_xor(bv, d);
          const int   oe = __shfl_xor(be, d);
          const int   oc = __shfl_xor(bc, d);
          if ((ov > bv) || ((ov == bv) && (oe < be))) { bv = ov; be = oe; bc = oc; }
        }
        const float sw = (float)cand_sv[bc];
        wsum += sw;
        if (lane == it) { myidx = be; mys = sw; }
        if (cA == bc) vA = -1e300;
        if (cB == bc) vB = -1e300;
      }
      if (lane < KSEL) {
        out[(size_t)(t0 + tk) * KSEL + lane] = (float)myidx;
        out[(size_t)NTOK * KSEL + (size_t)(t0 + tk) * KSEL + lane] =
            mys / (wsum + 1e-20f) * SCALE_F;
      }
    }
    __syncthreads();
  }
}

extern "C" void kernel_launch(void* const* d_in, const int* in_sizes, int n_in,
                              void* d_out, int out_size, void* d_ws, size_t ws_size,
                              hipStream_t stream) {
  (void)in_sizes; (void)n_in; (void)out_size;
  const float* xg = (const float*)d_in[0];
  const float* wg = (const float*)d_in[1];
  const float* bg = (const float*)d_in[2];
  float* out = (float*)d_out;

  const size_t need_t1 = PART8_BYTES + FLAG_BYTES + WPACK_BYTES;   // ~79 MB
  const size_t need_t2 = PART4_BYTES + FLAG_BYTES + WPACK_BYTES;   // ~47 MB
  const size_t need_t3 = PART4_BYTES + FLAG_BYTES;                 // ~32 MB

  if (ws_size >= need_t1) {
    // KS=8: grid 512 (2 blk/CU if regs <=128), single-buffer-B body
    float* part = (float*)d_ws;
    int* flaglist = (int*)((char*)d_ws + PART8_BYTES);
    unsigned short* wpack = (unsigned short*)((char*)d_ws + PART8_BYTES + FLAG_BYTES);
    hipLaunchKernelGGL(moe_wpack, dim3(NKT, 2), dim3(256), 0, stream, wg, wpack, flaglist);
    hipLaunchKernelGGL(moe_gemm_mfma8, dim3((NTOK / BT3) * 8), dim3(512), 0, stream,
                       xg, wpack, part);
    hipLaunchKernelGGL((moe_gate_from_part<8>), dim3(NTOK / BTG), dim3(256), 0, stream,
                       bg, part, flaglist, out, TAU_EMF, TAU_GMF);
    hipLaunchKernelGGL((moe_refine<8>), dim3(1024), dim3(256), 0, stream,
                       xg, wg, bg, part, flaglist, out);
  } else if (ws_size >= need_t2) {
    // KS=4: exact round-6 verified config (148 us gemm, (512,2))
    float* part = (float*)d_ws;
    int* flaglist = (int*)((char*)d_ws + PART4_BYTES);
    unsigned short* wpack = (unsigned short*)((char*)d_ws + PART4_BYTES + FLAG_BYTES);
    hipLaunchKernelGGL(moe_wpack, dim3(NKT, 2), dim3(256), 0, stream, wg, wpack, flaglist);
    hipLaunchKernelGGL(moe_gemm_mfma4, dim3((NTOK / BT3) * 4), dim3(512), 0, stream,
                       xg, wpack, part);
    hipLaunchKernelGGL((moe_gate_from_part<4>), dim3(NTOK / BTG), dim3(256), 0, stream,
                       bg, part, flaglist, out, TAU_EMF, TAU_GMF);
    hipLaunchKernelGGL((moe_refine<4>), dim3(1024), dim3(256), 0, stream,
                       xg, wg, bg, part, flaglist, out);
  } else if (ws_size >= need_t3) {
    float* part = (float*)d_ws;
    int* flaglist = (int*)((char*)d_ws + PART4_BYTES);
    hipLaunchKernelGGL(moe_gemm_part, dim3(NTOK / BT2, KS4), dim3(256), 0, stream,
                       xg, wg, part, flaglist);
    hipLaunchKernelGGL((moe_gate_from_part<4>), dim3(NTOK / BTG), dim3(256), 0, stream,
                       bg, part, flaglist, out, TAU_E32, TAU_G32);
    hipLaunchKernelGGL((moe_refine<4>), dim3(1024), dim3(256), 0, stream,
                       xg, wg, bg, part, flaglist, out);
  } else {
    hipLaunchKernelGGL(moe_gate_fused, dim3(NTOK / BT), dim3(NTHR), 0, stream,
                       xg, wg, bg, out);
  }
}